// Round 6
// baseline (1087.438 us; speedup 1.0000x reference)
//
#include <hip/hip_runtime.h>
#include <stdint.h>

#define SCALE 0.17677669529663687f  // 32^-0.5

typedef __attribute__((ext_vector_type(8))) short short8;
typedef __attribute__((ext_vector_type(4))) float floatx4;

__device__ __forceinline__ unsigned short f2bf(float f) {
    union { float f; unsigned u; } v; v.f = f;
    unsigned r = (v.u + 0x7fffu + ((v.u >> 16) & 1u)) >> 16;  // RNE
    return (unsigned short)r;
}
// packed f32x2 -> bf16x2, RNE (identical numerics to f2bf)
__device__ __forceinline__ unsigned cvtpk(float lo, float hi) {
    unsigned d;
    asm("v_cvt_pk_bf16_f32 %0, %1, %2" : "=v"(d) : "v"(lo), "v"(hi));
    return d;
}
// XOR-swizzle (short-index): spreads 8 rows across 8 16B bank-slots
__device__ __forceinline__ int swz(int row, int idx) { return idx ^ ((row & 7) << 3); }

// ---------- prep: transpose weights to bf16 (W^T rows = output cols, contiguous K) ----------
__global__ void prep_weights(const float* __restrict__ qkv_w,
                             const float* __restrict__ proj_w,
                             unsigned short* __restrict__ qkv_wt,
                             unsigned short* __restrict__ proj_wt) {
    int i = blockIdx.x * blockDim.x + threadIdx.x;
    const int nq = 1152 * 384;
    const int np = 384 * 384;
    if (i < nq) {
        int r = i / 384, c = i - r * 384;          // qkv_wt[r][c] = qkv_w[c][r]
        qkv_wt[i] = f2bf(qkv_w[c * 1152 + r]);
    } else if (i < nq + np) {
        int o = i - nq;
        int r = o / 384, c = o - r * 384;
        proj_wt[o] = f2bf(proj_w[c * 384 + r]);
    }
}

// ---------- prep: relative-position bias table bt[h][i][j], 12x64x64 fp32 ----------
__global__ void prep_bias(const float* __restrict__ w1, const float* __restrict__ b1,
                          const float* __restrict__ w2, const float* __restrict__ b2,
                          float* __restrict__ bt) {
    int t = blockIdx.x * blockDim.x + threadIdx.x;  // 4096 threads
    int i = t >> 6, j = t & 63;
    float r0 = (float)((i >> 4) - (j >> 4));
    float r1 = (float)(((i >> 2) & 3) - ((j >> 2) & 3));
    float r2 = (float)((i & 3) - (j & 3));
    float acc[12];
#pragma unroll
    for (int h = 0; h < 12; ++h) acc[h] = b2[h];
    for (int u = 0; u < 64; ++u) {
        float hv = r0 * w1[u] + r1 * w1[64 + u] + r2 * w1[128 + u] + b1[u];
        hv = fmaxf(hv, 0.f);
#pragma unroll
        for (int h = 0; h < 12; ++h) acc[h] += hv * w2[u * 12 + h];
    }
    for (int h = 0; h < 12; ++h) bt[(h << 12) + (i << 6) + j] = acc[h];
}

// ---------- fused window attention: one block = one window, 384 threads / 6 waves ----------
// LDS = 65536 B exactly -> TWO independent blocks/CU (the occupancy lever).
// Per head h: [B1(h) || proj(h-1)] bar [B23(h): swapped-QK^T in-register softmax,
// P redistributed via cvt_pk + ds_bpermute (no P LDS buffer), O^T via mfma(vT, P)] bar.
__launch_bounds__(384, 3)
__global__ void win_attn(const float* __restrict__ x,
                         const unsigned short* __restrict__ qkv_wt,
                         const float* __restrict__ qkv_b,
                         const unsigned short* __restrict__ proj_wt,
                         const float* __restrict__ proj_b,
                         const float* __restrict__ bt,
                         float* __restrict__ out) {
    __shared__ unsigned short xs[64 * 384];   // x window bf16, swizzled   49152 B
    __shared__ unsigned short ql[64 * 32];    // q (current head)           4096 B
    __shared__ unsigned short kl[64 * 32];    // k (current head)           4096 B
    __shared__ unsigned short vt[32 * 64];    // v^T (current head)         4096 B
    __shared__ unsigned short osl[64 * 32];   // O slice 64x32              4096 B
                                              // total 65536 B -> 2 blocks/CU
    const int tid  = threadIdx.x;
    const int lane = tid & 63;
    const int w    = tid >> 6;     // wave 0..5
    const int l15  = lane & 15;
    const int quad = lane >> 4;
    const int b    = blockIdx.x;

    // ---- stage x -> bf16 LDS (coalesced float4, swizzled rows) ----
    const float* xb = x + (size_t)b * (64 * 384);
#pragma unroll
    for (int it = 0; it < 16; ++it) {
        int idx = it * 384 + tid;
        int row = idx / 96;                          // 96 float4 per row
        int c4  = idx - row * 96;
        const float4 v = *reinterpret_cast<const float4*>(xb + row * 384 + c4 * 4);
        uint2 pk;
        pk.x = (unsigned)f2bf(v.x) | ((unsigned)f2bf(v.y) << 16);
        pk.y = (unsigned)f2bf(v.z) | ((unsigned)f2bf(v.w) << 16);
        *reinterpret_cast<uint2*>(&xs[swz(row, row * 384 + c4 * 4)]) = pk;
    }
    __syncthreads();

    // B1 role: wave w owns one 16-wide N-tile of [q0 q1 k0 k1 v0 v1]
    const int j3 = w >> 1;         // 0=q, 1=k, 2=v
    const int d2 = w & 1;          // 16-wide d-half
    const int t0 = w * 4;          // proj: 4 N-tiles per wave (24 total)
    const floatx4 zf4 = {0.f, 0.f, 0.f, 0.f};

    floatx4 acc2[4][4];            // persistent proj accumulator
#pragma unroll
    for (int jj = 0; jj < 4; ++jj)
#pragma unroll
        for (int m = 0; m < 4; ++m) acc2[jj][m] = zf4;

// ---- proj(H): acc2 += osl @ proj_wt[:, H*32 .. H*32+32] ----
#define PROJ_STEP(H)                                                                    \
    {                                                                                   \
        short8 a2_[4];                                                                  \
        _Pragma("unroll")                                                               \
        for (int m = 0; m < 4; ++m)                                                     \
            a2_[m] = *reinterpret_cast<const short8*>(                                  \
                &osl[swz(l15, (16 * m + l15) * 32 + quad * 8)]);                        \
        _Pragma("unroll")                                                               \
        for (int jj = 0; jj < 4; ++jj) {                                                \
            const unsigned short* pw =                                                  \
                proj_wt + (size_t)((t0 + jj) * 16 + l15) * 384 + (H) * 32;              \
            const short8 b2_ = *reinterpret_cast<const short8*>(pw + quad * 8);         \
            _Pragma("unroll")                                                           \
            for (int m = 0; m < 4; ++m)                                                 \
                acc2[jj][m] = __builtin_amdgcn_mfma_f32_16x16x32_bf16(                  \
                    a2_[m], b2_, acc2[jj][m], 0, 0, 0);                                 \
        }                                                                               \
    }

#pragma unroll 1
    for (int h = 0; h < 12; ++h) {
        // ======== phase A: B1(h) || proj(h-1) ========
        floatx4 acc[4];
#pragma unroll
        for (int m = 0; m < 4; ++m) acc[m] = zf4;
        const int colbase = j3 * 384 + h * 32 + d2 * 16;
        const unsigned short* wcol = qkv_wt + (size_t)(colbase + l15) * 384;

#pragma unroll
        for (int kk = 0; kk < 12; ++kk) {
            const short8 bf = *reinterpret_cast<const short8*>(wcol + kk * 32 + quad * 8);
            short8 a[4];
#pragma unroll
            for (int m = 0; m < 4; ++m)
                a[m] = *reinterpret_cast<const short8*>(
                    &xs[swz(l15, (16 * m + l15) * 384 + kk * 32 + quad * 8)]);
#pragma unroll
            for (int m = 0; m < 4; ++m)
                acc[m] = __builtin_amdgcn_mfma_f32_16x16x32_bf16(a[m], bf, acc[m], 0, 0, 0);
        }
        if (h >= 1) PROJ_STEP(h - 1);   // reads osl(h-1), written pre-barrier last iter

        // B1 epilogue: +bias; q/k row-major [64][32], v transposed [32][64]
        {
            const float bc = qkv_b[colbase + l15];
            if (j3 < 2) {
                unsigned short* dst = (j3 == 0) ? ql : kl;
#pragma unroll
                for (int m = 0; m < 4; ++m)
#pragma unroll
                    for (int r = 0; r < 4; ++r) {
                        int tok = 16 * m + quad * 4 + r;
                        dst[swz(tok, tok * 32 + d2 * 16 + l15)] = f2bf(acc[m][r] + bc);
                    }
            } else {
                const int d = d2 * 16 + l15;
#pragma unroll
                for (int m = 0; m < 4; ++m) {
                    uint2 pk;
                    pk.x = cvtpk(acc[m][0] + bc, acc[m][1] + bc);
                    pk.y = cvtpk(acc[m][2] + bc, acc[m][3] + bc);
                    *reinterpret_cast<uint2*>(
                        &vt[swz(d, d * 64 + 16 * m + quad * 4)]) = pk;
                }
            }
        }
        __syncthreads();

        // ======== phase B: B23(h) on waves 0..3 (wave = 16-row block rb) ========
        if (w < 4) {
            const int rb = w;
            const int n  = 16 * rb + l15;            // this lane's q-token
            // swapped QK^T: S^T tiles -> lane holds S[n][m], m = 16c + 4*quad + r
            const short8 bq = *reinterpret_cast<const short8*>(
                &ql[swz(l15, n * 32 + quad * 8)]);
            floatx4 st[4];
#pragma unroll
            for (int c = 0; c < 4; ++c) {
                const short8 ak = *reinterpret_cast<const short8*>(
                    &kl[swz(l15, (16 * c + l15) * 32 + quad * 8)]);
                st[c] = __builtin_amdgcn_mfma_f32_16x16x32_bf16(ak, bq, zf4, 0, 0, 0);
            }
            // scale + bias (vectorized float4), in-register row softmax (2 shuffles)
            const float* bth = bt + ((size_t)h << 12) + (n << 6);
#pragma unroll
            for (int c = 0; c < 4; ++c) {
                const float4 bb = *reinterpret_cast<const float4*>(bth + 16 * c + 4 * quad);
#pragma unroll
                for (int r = 0; r < 4; ++r)
                    st[c][r] = st[c][r] * SCALE + ((const float*)&bb)[r];
            }
            float m0 = st[0][0];
#pragma unroll
            for (int c = 0; c < 4; ++c)
#pragma unroll
                for (int r = 0; r < 4; ++r) m0 = fmaxf(m0, st[c][r]);
            m0 = fmaxf(m0, __shfl_xor(m0, 16));
            m0 = fmaxf(m0, __shfl_xor(m0, 32));
            float p0 = 0.f;
            float p[4][4];
#pragma unroll
            for (int c = 0; c < 4; ++c)
#pragma unroll
                for (int r = 0; r < 4; ++r) {
                    p[c][r] = __expf(st[c][r] - m0);
                    p0 += p[c][r];
                }
            p0 += __shfl_xor(p0, 16);
            p0 += __shfl_xor(p0, 32);
            const float rs = 1.f / p0;

            // pack P to bf16 pairs, redistribute into PV B-fragments via ds_bpermute.
            // target lane (l15,qt) elem j needs m = 32kkp + 8qt + j:
            //   src lane = l15 + 16*(2(qt&1) + (j>=4)), tile c = 2kkp + (qt>>1), r = j&3
            unsigned upk[4][2];
#pragma unroll
            for (int c = 0; c < 4; ++c) {
                upk[c][0] = cvtpk(p[c][0], p[c][1]);
                upk[c][1] = cvtpk(p[c][2], p[c][3]);
            }
            const int addrA = (l15 + ((quad & 1) << 5)) << 2;  // lane l15 + 32*(qt&1)
            const int addrB = addrA + 64;                      // +16 lanes
            const bool hi = (quad & 2) != 0;                   // selects c = 2kkp+1
            short8 bp[2];
#pragma unroll
            for (int kkp = 0; kkp < 2; ++kkp) {
                const int c0 = 2 * kkp, c1 = c0 + 1;
                unsigned w0a = __builtin_amdgcn_ds_bpermute(addrA, upk[c0][0]);
                unsigned w0b = __builtin_amdgcn_ds_bpermute(addrA, upk[c1][0]);
                unsigned w1a = __builtin_amdgcn_ds_bpermute(addrA, upk[c0][1]);
                unsigned w1b = __builtin_amdgcn_ds_bpermute(addrA, upk[c1][1]);
                unsigned w2a = __builtin_amdgcn_ds_bpermute(addrB, upk[c0][0]);
                unsigned w2b = __builtin_amdgcn_ds_bpermute(addrB, upk[c1][0]);
                unsigned w3a = __builtin_amdgcn_ds_bpermute(addrB, upk[c0][1]);
                unsigned w3b = __builtin_amdgcn_ds_bpermute(addrB, upk[c1][1]);
                union { unsigned u[4]; short8 s; } uu;
                uu.u[0] = hi ? w0b : w0a;
                uu.u[1] = hi ? w1b : w1a;
                uu.u[2] = hi ? w2b : w2a;
                uu.u[3] = hi ? w3b : w3a;
                bp[kkp] = uu.s;
            }
            // PV: O^T = mfma(vT-frag, P-frag); lane holds O[n][16t+4*quad+r]
#pragma unroll
            for (int t = 0; t < 2; ++t) {
                floatx4 oacc = zf4;
#pragma unroll
                for (int kkp = 0; kkp < 2; ++kkp) {
                    const short8 av = *reinterpret_cast<const short8*>(
                        &vt[swz(l15, (16 * t + l15) * 64 + kkp * 32 + quad * 8)]);
                    oacc = __builtin_amdgcn_mfma_f32_16x16x32_bf16(av, bp[kkp], oacc, 0, 0, 0);
                }
                uint2 pk;
                pk.x = cvtpk(oacc[0] * rs, oacc[1] * rs);
                pk.y = cvtpk(oacc[2] * rs, oacc[3] * rs);
                *reinterpret_cast<uint2*>(
                    &osl[swz(l15, n * 32 + 16 * t + 4 * quad)]) = pk;
            }
        }
        __syncthreads();
    }

    // ======== final proj(11): osl stable (read-only past here) ========
    PROJ_STEP(11);

    // ======== epilogue: out = acc2 + proj_b ========
    float* ob = out + (size_t)b * (64 * 384);
#pragma unroll
    for (int jj = 0; jj < 4; ++jj) {
        const int col = (t0 + jj) * 16 + l15;
        const float pbias = proj_b[col];
#pragma unroll
        for (int m = 0; m < 4; ++m)
#pragma unroll
            for (int r = 0; r < 4; ++r)
                ob[(16 * m + quad * 4 + r) * 384 + col] = acc2[jj][m][r] + pbias;
    }
#undef PROJ_STEP
}

extern "C" void kernel_launch(void* const* d_in, const int* in_sizes, int n_in,
                              void* d_out, int out_size, void* d_ws, size_t ws_size,
                              hipStream_t stream) {
    const float* x      = (const float*)d_in[0];
    const float* qkv_w  = (const float*)d_in[1];
    const float* qkv_b  = (const float*)d_in[2];
    const float* proj_w = (const float*)d_in[3];
    const float* proj_b = (const float*)d_in[4];
    const float* mlp_w1 = (const float*)d_in[5];
    const float* mlp_b1 = (const float*)d_in[6];
    const float* mlp_w2 = (const float*)d_in[7];
    const float* mlp_b2 = (const float*)d_in[8];
    float* out = (float*)d_out;

    // workspace layout (re-written every launch; harness poisons ws)
    unsigned short* qkv_wt  = (unsigned short*)d_ws;              // 1152*384 bf16
    unsigned short* proj_wt = qkv_wt + 1152 * 384;                // 384*384 bf16
    float*          bt      = (float*)(proj_wt + 384 * 384);      // 12*64*64 fp32

    prep_weights<<<2304, 256, 0, stream>>>(qkv_w, proj_w, qkv_wt, proj_wt);
    prep_bias<<<16, 256, 0, stream>>>(mlp_w1, mlp_b1, mlp_w2, mlp_b2, bt);
    win_attn<<<2048, 384, 0, stream>>>(x, qkv_wt, qkv_b, proj_wt, proj_b, bt, out);
}

// Round 7
// 739.546 us; speedup vs baseline: 1.4704x; 1.4704x over previous
//
#include <hip/hip_runtime.h>
#include <stdint.h>

#define SCALE 0.17677669529663687f  // 32^-0.5

typedef __attribute__((ext_vector_type(8))) short short8;
typedef __attribute__((ext_vector_type(4))) float floatx4;
typedef __attribute__((ext_vector_type(4))) unsigned uintx4;

__device__ __forceinline__ unsigned short f2bf(float f) {
    union { float f; unsigned u; } v; v.f = f;
    unsigned r = (v.u + 0x7fffu + ((v.u >> 16) & 1u)) >> 16;  // RNE
    return (unsigned short)r;
}
// packed f32x2 -> bf16x2, RNE (identical numerics to f2bf; verified round 6)
__device__ __forceinline__ unsigned cvtpk(float lo, float hi) {
    unsigned d;
    asm("v_cvt_pk_bf16_f32 %0, %1, %2" : "=v"(d) : "v"(lo), "v"(hi));
    return d;
}

// ---------- prep: coalesced 32x32 LDS-tile transpose, f32 -> bf16 ----------
// qkv_w [384][1152] -> qkv_wt [1152][384]; proj_w [384][384] -> proj_wt [384][384]
__global__ void prep_weights(const float* __restrict__ qkv_w,
                             const float* __restrict__ proj_w,
                             unsigned short* __restrict__ qkv_wt,
                             unsigned short* __restrict__ proj_wt) {
    __shared__ float t[32][33];
    const int tile = blockIdx.x;                 // 0..431 qkv, 432..575 proj
    const int idx = threadIdx.x;
    const int j = idx & 31, i0 = idx >> 5;       // 8 rows per pass
    if (tile < 432) {
        const int tc = tile / 36, tr = tile - tc * 36;   // c-tile 0..11, r-tile 0..35
#pragma unroll
        for (int pass = 0; pass < 4; ++pass) {
            int i = i0 + pass * 8;
            t[i][j] = qkv_w[(tc * 32 + i) * 1152 + tr * 32 + j];
        }
        __syncthreads();
#pragma unroll
        for (int pass = 0; pass < 4; ++pass) {
            int i = i0 + pass * 8;
            qkv_wt[(tr * 32 + i) * 384 + tc * 32 + j] = f2bf(t[j][i]);
        }
    } else {
        const int t2 = tile - 432;
        const int tc = t2 / 12, tr = t2 - tc * 12;
#pragma unroll
        for (int pass = 0; pass < 4; ++pass) {
            int i = i0 + pass * 8;
            t[i][j] = proj_w[(tc * 32 + i) * 384 + tr * 32 + j];
        }
        __syncthreads();
#pragma unroll
        for (int pass = 0; pass < 4; ++pass) {
            int i = i0 + pass * 8;
            proj_wt[(tr * 32 + i) * 384 + tc * 32 + j] = f2bf(t[j][i]);
        }
    }
}

// ---------- prep: relative-position bias table bt[h][i][j], 12x64x64 fp32 ----------
__global__ void prep_bias(const float* __restrict__ w1, const float* __restrict__ b1,
                          const float* __restrict__ w2, const float* __restrict__ b2,
                          float* __restrict__ bt) {
    int t = blockIdx.x * blockDim.x + threadIdx.x;  // 4096 threads
    int i = t >> 6, j = t & 63;
    float r0 = (float)((i >> 4) - (j >> 4));
    float r1 = (float)(((i >> 2) & 3) - ((j >> 2) & 3));
    float r2 = (float)((i & 3) - (j & 3));
    float acc[12];
#pragma unroll
    for (int h = 0; h < 12; ++h) acc[h] = b2[h];
    for (int u = 0; u < 64; ++u) {
        float hv = r0 * w1[u] + r1 * w1[64 + u] + r2 * w1[128 + u] + b1[u];
        hv = fmaxf(hv, 0.f);
#pragma unroll
        for (int h = 0; h < 12; ++h) acc[h] += hv * w2[u * 12 + h];
    }
    for (int h = 0; h < 12; ++h) bt[(h << 12) + (i << 6) + j] = acc[h];
}

// ---------- fused window attention: one block = one window, 384 threads / 6 waves ----------
// Round-5 pair pipeline {B1(p) || B23(p-1) || proj(p-2)}, 8 barriers, PLUS round-6's
// verified swapped-QK^T in-register softmax + ds_bpermute P redistribution (pb buffer
// eliminated; fragments assembled via ext_vector/bit_cast, NOT union -> no scratch).
#define XP  392   // xs row stride (384+8 shorts)
#define QKP 40    // q/k row stride (32+8)
#define VTP 72    // vT row stride (64+8)
#define OSP 72    // osl row stride (64+8): 64 cols = 2 heads x 32d

__launch_bounds__(384, 2)
__global__ void win_attn(const float* __restrict__ x,
                         const unsigned short* __restrict__ qkv_wt,
                         const float* __restrict__ qkv_b,
                         const unsigned short* __restrict__ proj_wt,
                         const float* __restrict__ proj_b,
                         const float* __restrict__ bt,
                         float* __restrict__ out) {
    __shared__ unsigned short xs[64 * XP];            // x window bf16       50176 B
    __shared__ unsigned short ql[2][2][64 * QKP];     // q [pairbuf][head]   20480 B
    __shared__ unsigned short kl[2][2][64 * QKP];     // k                   20480 B
    __shared__ unsigned short vt[2][2][32 * VTP];     // v^T                 18432 B
    __shared__ unsigned short osl[2][64 * OSP];       // O pair-slice, dbuf  18432 B
                                                      // total 128000 B -> 1 block/CU
    const int tid  = threadIdx.x;
    const int lane = tid & 63;
    const int w    = tid >> 6;     // wave 0..5
    const int l15  = lane & 15;
    const int quad = lane >> 4;
    const int b    = blockIdx.x;

    // ---- stage x -> bf16 LDS (coalesced float4) ----
    const float* xb = x + (size_t)b * (64 * 384);
#pragma unroll
    for (int it = 0; it < 16; ++it) {
        int idx = it * 384 + tid;
        int row = idx / 96;                          // 96 float4 per row
        int c4  = idx - row * 96;
        const float4 v = *reinterpret_cast<const float4*>(xb + row * 384 + c4 * 4);
        uint2 pk;
        pk.x = cvtpk(v.x, v.y);
        pk.y = cvtpk(v.z, v.w);
        *reinterpret_cast<uint2*>(&xs[row * XP + c4 * 4]) = pk;
    }
    __syncthreads();

    // B1 role: wave w -> (q/k/v) = w>>1, d-half = w&1; both heads of the pair.
    const int j3 = w >> 1;
    const int d2 = w & 1;
    // proj role: waves 0-3 own 5 N-tiles, waves 4-5 own 2 (balances extra B23 on 4,5)
    const int ntile = (w < 4) ? 5 : 2;
    const int t0    = (w < 4) ? 5 * w : (20 + 2 * (w - 4));
    // B23 roles (fixed per wave): task0 = (h0, rb0); task1 = (1, w-2) for waves 4,5
    const int h0  = (w < 4) ? 0 : 1;
    const int rb0 = (w < 4) ? w : (w - 4);

    const floatx4 zf4 = {0.f, 0.f, 0.f, 0.f};
    floatx4 acc2[5][4];            // persistent proj accumulator
#pragma unroll
    for (int jj = 0; jj < 5; ++jj)
#pragma unroll
        for (int m = 0; m < 4; ++m) acc2[jj][m] = zf4;

// ---- proj(PP): acc2 += osl[PP&1] @ proj_wt[:, PP*64 .. PP*64+64] ----
#define PROJ_STEP(PP)                                                                   \
    {                                                                                   \
        const int buf_ = (PP) & 1;                                                      \
        short8 a2_[4][2];                                                               \
        _Pragma("unroll")                                                               \
        for (int m = 0; m < 4; ++m)                                                     \
            _Pragma("unroll")                                                           \
            for (int k2 = 0; k2 < 2; ++k2)                                              \
                a2_[m][k2] = *reinterpret_cast<const short8*>(                          \
                    &osl[buf_][(16 * m + l15) * OSP + k2 * 32 + quad * 8]);             \
        _Pragma("unroll")                                                               \
        for (int jj = 0; jj < 5; ++jj)                                                  \
            if (jj < ntile) {                                                           \
                const unsigned short* pw =                                              \
                    proj_wt + (size_t)((t0 + jj) * 16 + l15) * 384 + (PP) * 64;         \
                const short8 b20 = *reinterpret_cast<const short8*>(pw + quad * 8);     \
                const short8 b21 = *reinterpret_cast<const short8*>(pw + 32 + quad * 8);\
                _Pragma("unroll")                                                       \
                for (int m = 0; m < 4; ++m) {                                           \
                    acc2[jj][m] = __builtin_amdgcn_mfma_f32_16x16x32_bf16(              \
                        a2_[m][0], b20, acc2[jj][m], 0, 0, 0);                          \
                    acc2[jj][m] = __builtin_amdgcn_mfma_f32_16x16x32_bf16(              \
                        a2_[m][1], b21, acc2[jj][m], 0, 0, 0);                          \
                }                                                                       \
            }                                                                           \
    }

// ---- B23 task (swapped QK^T, in-register softmax, bpermute P, PV as O^T) ----
// Lane layout (verified on HW, round 6): st[c] reg r = S[q=16RB+l15][k=16c+4quad+r].
#define B23_TASK(H, RB, PP, RBUF)                                                       \
    {                                                                                   \
        const int n_ = 16 * (RB) + l15;                                                 \
        const short8 bq_ = *reinterpret_cast<const short8*>(                            \
            &ql[RBUF][H][n_ * QKP + quad * 8]);                                         \
        floatx4 st_[4];                                                                 \
        _Pragma("unroll")                                                               \
        for (int c = 0; c < 4; ++c) {                                                   \
            const short8 ak_ = *reinterpret_cast<const short8*>(                        \
                &kl[RBUF][H][(16 * c + l15) * QKP + quad * 8]);                         \
            st_[c] = __builtin_amdgcn_mfma_f32_16x16x32_bf16(ak_, bq_, zf4, 0, 0, 0);   \
        }                                                                               \
        const float* bth_ = bt + ((size_t)(2 * (PP) + (H)) << 12) + (n_ << 6);          \
        _Pragma("unroll")                                                               \
        for (int c = 0; c < 4; ++c) {                                                   \
            const float4 bb_ = *reinterpret_cast<const float4*>(bth_ + 16 * c + 4 * quad); \
            st_[c][0] = st_[c][0] * SCALE + bb_.x;                                      \
            st_[c][1] = st_[c][1] * SCALE + bb_.y;                                      \
            st_[c][2] = st_[c][2] * SCALE + bb_.z;                                      \
            st_[c][3] = st_[c][3] * SCALE + bb_.w;                                      \
        }                                                                               \
        float m0_ = st_[0][0];                                                          \
        _Pragma("unroll")                                                               \
        for (int c = 0; c < 4; ++c)                                                     \
            _Pragma("unroll")                                                           \
            for (int r = 0; r < 4; ++r) m0_ = fmaxf(m0_, st_[c][r]);                    \
        m0_ = fmaxf(m0_, __shfl_xor(m0_, 16));                                          \
        m0_ = fmaxf(m0_, __shfl_xor(m0_, 32));                                          \
        float p0_ = 0.f;                                                                \
        float p_[4][4];                                                                 \
        _Pragma("unroll")                                                               \
        for (int c = 0; c < 4; ++c)                                                     \
            _Pragma("unroll")                                                           \
            for (int r = 0; r < 4; ++r) {                                               \
                p_[c][r] = __expf(st_[c][r] - m0_);                                     \
                p0_ += p_[c][r];                                                        \
            }                                                                           \
        p0_ += __shfl_xor(p0_, 16);                                                     \
        p0_ += __shfl_xor(p0_, 32);                                                     \
        const float rs_ = 1.f / p0_;                                                    \
        unsigned upk_[4][2];                                                            \
        _Pragma("unroll")                                                               \
        for (int c = 0; c < 4; ++c) {                                                   \
            upk_[c][0] = cvtpk(p_[c][0], p_[c][1]);                                     \
            upk_[c][1] = cvtpk(p_[c][2], p_[c][3]);                                     \
        }                                                                               \
        const int addrA_ = (l15 + ((quad & 1) << 5)) << 2;                              \
        const int addrB_ = addrA_ + 64;                                                 \
        const bool hi_ = (quad & 2) != 0;                                               \
        short8 bp_[2];                                                                  \
        _Pragma("unroll")                                                               \
        for (int kkp = 0; kkp < 2; ++kkp) {                                             \
            const int c0_ = 2 * kkp, c1_ = c0_ + 1;                                     \
            unsigned w0a = __builtin_amdgcn_ds_bpermute(addrA_, upk_[c0_][0]);          \
            unsigned w0b = __builtin_amdgcn_ds_bpermute(addrA_, upk_[c1_][0]);          \
            unsigned w1a = __builtin_amdgcn_ds_bpermute(addrA_, upk_[c0_][1]);          \
            unsigned w1b = __builtin_amdgcn_ds_bpermute(addrA_, upk_[c1_][1]);          \
            unsigned w2a = __builtin_amdgcn_ds_bpermute(addrB_, upk_[c0_][0]);          \
            unsigned w2b = __builtin_amdgcn_ds_bpermute(addrB_, upk_[c1_][0]);          \
            unsigned w3a = __builtin_amdgcn_ds_bpermute(addrB_, upk_[c0_][1]);          \
            unsigned w3b = __builtin_amdgcn_ds_bpermute(addrB_, upk_[c1_][1]);          \
            uintx4 uu_;                                                                 \
            uu_.x = hi_ ? w0b : w0a;                                                    \
            uu_.y = hi_ ? w1b : w1a;                                                    \
            uu_.z = hi_ ? w2b : w2a;                                                    \
            uu_.w = hi_ ? w3b : w3a;                                                    \
            bp_[kkp] = __builtin_bit_cast(short8, uu_);                                 \
        }                                                                               \
        _Pragma("unroll")                                                               \
        for (int t = 0; t < 2; ++t) {                                                   \
            floatx4 oacc_ = zf4;                                                        \
            _Pragma("unroll")                                                           \
            for (int kkp = 0; kkp < 2; ++kkp) {                                         \
                const short8 av_ = *reinterpret_cast<const short8*>(                    \
                    &vt[RBUF][H][(16 * t + l15) * VTP + kkp * 32 + quad * 8]);          \
                oacc_ = __builtin_amdgcn_mfma_f32_16x16x32_bf16(av_, bp_[kkp], oacc_, 0, 0, 0); \
            }                                                                           \
            uint2 pk_;                                                                  \
            pk_.x = cvtpk(oacc_[0] * rs_, oacc_[1] * rs_);                              \
            pk_.y = cvtpk(oacc_[2] * rs_, oacc_[3] * rs_);                              \
            *reinterpret_cast<uint2*>(                                                  \
                &osl[(PP) & 1][n_ * OSP + (H) * 32 + 16 * t + 4 * quad]) = pk_;         \
        }                                                                               \
    }

#pragma unroll 1
    for (int p = 0; p < 6; ++p) {
        const int ob = p & 1;
        // ======== B1(p): q,k,v for heads 2p, 2p+1 -> buffers [ob] ========
        {
            floatx4 acc[2][4];
#pragma unroll
            for (int hh = 0; hh < 2; ++hh)
#pragma unroll
                for (int m = 0; m < 4; ++m) acc[hh][m] = zf4;

            int colbase[2];
#pragma unroll
            for (int hh = 0; hh < 2; ++hh)
                colbase[hh] = j3 * 384 + (2 * p + hh) * 32 + d2 * 16;
            const unsigned short* wcol0 = qkv_wt + (size_t)(colbase[0] + l15) * 384;
            const unsigned short* wcol1 = qkv_wt + (size_t)(colbase[1] + l15) * 384;

#pragma unroll
            for (int kk = 0; kk < 12; ++kk) {
                short8 a[4];
#pragma unroll
                for (int m = 0; m < 4; ++m)
                    a[m] = *reinterpret_cast<const short8*>(
                        &xs[(16 * m + l15) * XP + kk * 32 + quad * 8]);
                const short8 bf0 = *reinterpret_cast<const short8*>(wcol0 + kk * 32 + quad * 8);
                const short8 bf1 = *reinterpret_cast<const short8*>(wcol1 + kk * 32 + quad * 8);
#pragma unroll
                for (int m = 0; m < 4; ++m) {
                    acc[0][m] = __builtin_amdgcn_mfma_f32_16x16x32_bf16(a[m], bf0, acc[0][m], 0, 0, 0);
                    acc[1][m] = __builtin_amdgcn_mfma_f32_16x16x32_bf16(a[m], bf1, acc[1][m], 0, 0, 0);
                }
            }
            // epilogue: +bias; q/k row-major, v transposed (packed 8B stores)
#pragma unroll
            for (int hh = 0; hh < 2; ++hh) {
                const float bc = qkv_b[colbase[hh] + l15];
                if (j3 < 2) {
                    unsigned short* dst = (j3 == 0) ? ql[ob][hh] : kl[ob][hh];
#pragma unroll
                    for (int m = 0; m < 4; ++m)
#pragma unroll
                        for (int r = 0; r < 4; ++r)
                            dst[(16 * m + quad * 4 + r) * QKP + d2 * 16 + l15] =
                                f2bf(acc[hh][m][r] + bc);
                } else {
#pragma unroll
                    for (int m = 0; m < 4; ++m) {
                        uint2 pk;
                        pk.x = cvtpk(acc[hh][m][0] + bc, acc[hh][m][1] + bc);
                        pk.y = cvtpk(acc[hh][m][2] + bc, acc[hh][m][3] + bc);
                        *reinterpret_cast<uint2*>(
                            &vt[ob][hh][(d2 * 16 + l15) * VTP + 16 * m + quad * 4]) = pk;
                    }
                }
            }
        }
        // ======== B23(p-1): reads buffers [ob^1], writes osl[(p-1)&1] ========
        if (p >= 1) {
            const int rob = ob ^ 1;
            B23_TASK(h0, rb0, (p - 1), rob);
            if (w >= 4) B23_TASK(1, (w - 2), (p - 1), rob);
        }
        // ======== proj(p-2): reads osl[p&1] ========
        if (p >= 2) PROJ_STEP(p - 2);
        __syncthreads();
    }

    // ======== epilogue: B23(5), proj(4), barrier, proj(5) ========
    {
        B23_TASK(h0, rb0, 5, 1);
        if (w >= 4) B23_TASK(1, (w - 2), 5, 1);
        PROJ_STEP(4);
        __syncthreads();
        PROJ_STEP(5);
    }

    // ======== out = acc2 + proj_b ========
    float* ob_ptr = out + (size_t)b * (64 * 384);
#pragma unroll
    for (int jj = 0; jj < 5; ++jj)
        if (jj < ntile) {
            const int col = (t0 + jj) * 16 + l15;
            const float pbias = proj_b[col];
#pragma unroll
            for (int m = 0; m < 4; ++m)
#pragma unroll
                for (int r = 0; r < 4; ++r)
                    ob_ptr[(16 * m + quad * 4 + r) * 384 + col] = acc2[jj][m][r] + pbias;
        }
#undef PROJ_STEP
#undef B23_TASK
}

extern "C" void kernel_launch(void* const* d_in, const int* in_sizes, int n_in,
                              void* d_out, int out_size, void* d_ws, size_t ws_size,
                              hipStream_t stream) {
    const float* x      = (const float*)d_in[0];
    const float* qkv_w  = (const float*)d_in[1];
    const float* qkv_b  = (const float*)d_in[2];
    const float* proj_w = (const float*)d_in[3];
    const float* proj_b = (const float*)d_in[4];
    const float* mlp_w1 = (const float*)d_in[5];
    const float* mlp_b1 = (const float*)d_in[6];
    const float* mlp_w2 = (const float*)d_in[7];
    const float* mlp_b2 = (const float*)d_in[8];
    float* out = (float*)d_out;

    // workspace layout (re-written every launch; harness poisons ws)
    unsigned short* qkv_wt  = (unsigned short*)d_ws;              // 1152*384 bf16
    unsigned short* proj_wt = qkv_wt + 1152 * 384;                // 384*384 bf16
    float*          bt      = (float*)(proj_wt + 384 * 384);      // 12*64*64 fp32

    prep_weights<<<576, 256, 0, stream>>>(qkv_w, proj_w, qkv_wt, proj_wt);
    prep_bias<<<16, 256, 0, stream>>>(mlp_w1, mlp_b1, mlp_w2, mlp_b2, bt);
    win_attn<<<2048, 384, 0, stream>>>(x, qkv_wt, qkv_b, proj_wt, proj_b, bt, out);
}